// Round 2
// baseline (68.231 us; speedup 1.0000x reference)
//
#include <hip/hip_runtime.h>
#include <hip/hip_bf16.h>
#include <stdint.h>

#define N_W 96
#define N_F 96
#define NAG 192                      // total agents
#define NP1 97
#define W_ELEMS (N_W * NP1 * NP1)    // 903264 (divisible by 4)
#define R_ELEMS (NAG * NAG)          // 36864
#define WB ((W_ELEMS / 4 + 255) / 256)   // blocks per W/F section (883)
#define RB ((R_ELEMS / 4 + 255) / 256)   // 36

// Decode one-hot tensors into packed index form.
// packed word [a*64 + s] = pref[a][s] | (pref[a][s+64] << 16)  (high half valid for s<33)
// ord[r] = dictating agent in round r (0..95 worker, 96..191 firm).
__global__ __launch_bounds__(256) void decode_kernel(
    const float* __restrict__ W, const float* __restrict__ F,
    const float* __restrict__ R,
    short* __restrict__ ps /* aliases packed u32 array */, short* __restrict__ ord) {
    int b = blockIdx.x;
    if (b < 2 * WB) {
        const float* src = (b < WB) ? W : F;
        int abase = (b < WB) ? 0 : N_W;
        int i4 = (b - ((b < WB) ? 0 : WB)) * 256 + threadIdx.x;
        if (i4 < W_ELEMS / 4) {
            float4 v = ((const float4*)src)[i4];
            int base = i4 * 4;
            #pragma unroll
            for (int u = 0; u < 4; ++u) {
                float x = (u == 0) ? v.x : (u == 1) ? v.y : (u == 2) ? v.z : v.w;
                if (x > 0.5f) {
                    int idx = base + u;
                    int a = idx / (NP1 * NP1);
                    int rem = idx - a * (NP1 * NP1);
                    int j = rem / NP1;          // option (firm/worker or 96=unmatch)
                    int k = rem - j * NP1;      // rank
                    int slot = (k < 64) ? (2 * k) : (2 * (k - 64) + 1);
                    ps[(abase + a) * 128 + slot] = (short)j;
                }
            }
        }
    } else {
        int i4 = (b - 2 * WB) * 256 + threadIdx.x;
        if (i4 < R_ELEMS / 4) {
            float4 v = ((const float4*)R)[i4];
            int base = i4 * 4;
            #pragma unroll
            for (int u = 0; u < 4; ++u) {
                float x = (u == 0) ? v.x : (u == 1) ? v.y : (u == 2) ? v.z : v.w;
                if (x > 0.5f) {
                    int idx = base + u;
                    int a = idx / NAG;
                    int r = idx - a * NAG;
                    ord[r] = (short)a;
                }
            }
        }
    }
}

// Single-block sequential serial dictatorship, register-resident state.
__global__ __launch_bounds__(256) void sd_kernel(
    const uint32_t* __restrict__ pk_g, const short* __restrict__ ord_g,
    float* __restrict__ out) {
    __shared__ __align__(16) uint32_t s_pk[NAG * 64];   // 48 KiB packed prefs
    __shared__ uint4 s_ordq[24];                        // 192 shorts
    __shared__ uint32_t s_match[NAG];                   // matched cell per round, ~0 = none

    const int t = threadIdx.x;
    for (int i = t; i < NAG * 64 / 4; i += 256)
        ((uint4*)s_pk)[i] = ((const uint4*)pk_g)[i];
    if (t < 24) s_ordq[t] = ((const uint4*)ord_g)[t];
    if (t < NAG) s_match[t] = 0xFFFFFFFFu;
    __syncthreads();

    if (t < 64) {
        // availability (rem) and annihilation (zero) bitmasks, wave-uniform
        unsigned long long remF_lo = 0, remF_hi = 0, remW_lo = 0, remW_hi = 0;
        unsigned long long zF_lo = 0, zF_hi = 0, zW_lo = 0, zW_hi = 0;

        auto process = [&](int r, int a_in, uint32_t p) {
            int a = __builtin_amdgcn_readfirstlane(a_in);
            bool isW = a < N_W;
            int aa = isW ? a : (a - N_W);
            bool lo = aa < 64;
            unsigned long long sbit = 1ull << (aa & 63);
            unsigned long long s_lo = lo ? sbit : 0ull;
            unsigned long long s_hi = lo ? 0ull : sbit;
            // zero (annihilated) check
            unsigned long long zl = isW ? zW_lo : zF_lo;
            unsigned long long zh = isW ? zW_hi : zF_hi;
            bool dead = (((lo ? zl : zh) >> (aa & 63)) & 1ull) != 0;
            // self removal from the OTHER side's lists (always happens)
            remW_lo |= isW ? s_lo : 0ull;  remW_hi |= isW ? s_hi : 0ull;
            remF_lo |= isW ? 0ull : s_lo;  remF_hi |= isW ? 0ull : s_hi;
            // first available choice
            unsigned long long o_lo = isW ? remF_lo : remW_lo;
            unsigned long long o_hi = isW ? remF_hi : remW_hi;
            int j1 = (int)(p & 0xFFFFu);
            int j2 = (int)(p >> 16);
            bool av1 = ((((j1 < 64) ? o_lo : o_hi) >> (j1 & 63)) & 1ull) == 0;
            bool av2 = (t < 33) && (((((j2 < 64) ? o_lo : o_hi) >> (j2 & 63)) & 1ull) == 0);
            unsigned long long m1 = __ballot(av1);
            unsigned long long m2 = __ballot(av2);
            int k = (m1 != 0) ? (__ffsll((unsigned long long)m1) - 1)
                              : (63 + __ffsll((unsigned long long)m2));
            uint32_t pc = (uint32_t)__builtin_amdgcn_readlane((int)p, k & 63);
            int js = (k < 64) ? (int)(pc & 0xFFFFu) : (int)(pc >> 16);
            int cell = isW ? (aa * NP1 + js) : (js * NP1 + aa);
            s_match[r] = dead ? 0xFFFFFFFFu : (uint32_t)cell;
            // remove + annihilate the chosen counterpart (if not unmatch)
            bool take = (!dead) && (js < 96);
            unsigned long long cbit = take ? (1ull << (js & 63)) : 0ull;
            bool clo = js < 64;
            unsigned long long c_lo = clo ? cbit : 0ull;
            unsigned long long c_hi = clo ? 0ull : cbit;
            remF_lo |= isW ? c_lo : 0ull;  remF_hi |= isW ? c_hi : 0ull;
            zF_lo   |= isW ? c_lo : 0ull;  zF_hi   |= isW ? c_hi : 0ull;
            remW_lo |= isW ? 0ull : c_lo;  remW_hi |= isW ? 0ull : c_hi;
            zW_lo   |= isW ? 0ull : c_lo;  zW_hi   |= isW ? 0ull : c_hi;
        };

        // pipeline: group g (8 rounds) processed while group g+1's prefs load
        uint4 oq = s_ordq[0];
        int ag[8];
        ag[0] = (int)(oq.x & 0xFFFF); ag[1] = (int)(oq.x >> 16);
        ag[2] = (int)(oq.y & 0xFFFF); ag[3] = (int)(oq.y >> 16);
        ag[4] = (int)(oq.z & 0xFFFF); ag[5] = (int)(oq.z >> 16);
        ag[6] = (int)(oq.w & 0xFFFF); ag[7] = (int)(oq.w >> 16);
        uint32_t pp[8];
        #pragma unroll
        for (int i = 0; i < 8; ++i) pp[i] = s_pk[ag[i] * 64 + t];

        for (int g = 0; g < 24; ++g) {
            int agn[8] = {0, 0, 0, 0, 0, 0, 0, 0};
            uint32_t ppn[8] = {0, 0, 0, 0, 0, 0, 0, 0};
            if (g < 23) {
                uint4 oqn = s_ordq[g + 1];
                agn[0] = (int)(oqn.x & 0xFFFF); agn[1] = (int)(oqn.x >> 16);
                agn[2] = (int)(oqn.y & 0xFFFF); agn[3] = (int)(oqn.y >> 16);
                agn[4] = (int)(oqn.z & 0xFFFF); agn[5] = (int)(oqn.z >> 16);
                agn[6] = (int)(oqn.w & 0xFFFF); agn[7] = (int)(oqn.w >> 16);
                #pragma unroll
                for (int i = 0; i < 8; ++i) ppn[i] = s_pk[agn[i] * 64 + t];
            }
            #pragma unroll
            for (int i = 0; i < 8; ++i) process(g * 8 + i, ag[i], pp[i]);
            #pragma unroll
            for (int i = 0; i < 8; ++i) { ag[i] = agn[i]; pp[i] = ppn[i]; }
        }
    }
    __syncthreads();

    // zero-fill output (9409 floats = 2352 float4 + 1)
    for (int i = t; i < 2352; i += 256)
        ((float4*)out)[i] = make_float4(0.f, 0.f, 0.f, 0.f);
    if (t == 0) out[9408] = 0.f;
    __syncthreads();
    if (t < NAG) {
        uint32_t c = s_match[t];
        if (c != 0xFFFFFFFFu) out[c] = 1.0f;
    }
}

extern "C" void kernel_launch(void* const* d_in, const int* in_sizes, int n_in,
                              void* d_out, int out_size, void* d_ws, size_t ws_size,
                              hipStream_t stream) {
    const float* W = (const float*)d_in[0];
    const float* F = (const float*)d_in[1];
    const float* R = (const float*)d_in[2];
    float* out = (float*)d_out;

    uint32_t* packed = (uint32_t*)d_ws;                 // NAG*64 u32 = 48 KiB
    short* ord = (short*)((char*)d_ws + NAG * 64 * 4);  // 192 shorts

    decode_kernel<<<2 * WB + RB, 256, 0, stream>>>(W, F, R, (short*)packed, ord);
    sd_kernel<<<1, 256, 0, stream>>>(packed, ord, out);
}